// Round 1
// baseline (218.029 us; speedup 1.0000x reference)
//
#include <hip/hip_runtime.h>
#include <hip/hip_cooperative_groups.h>
#include <math.h>

namespace cg = cooperative_groups;

#define N_NODES 262144
#define N_EDGES 2097152
#define NB 512                  // dst buckets (dst >> 9), 512 nodes each
#define NAH 256                 // sort slice blocks
#define EPB (N_EDGES / NAH)     // 8192 edges per slice
#define CAP 8192                // per-bucket region capacity in elist2 (avg 4096, +64 sigma)
#define HID 200
#define G_TAB 128
#define RLO (-8.0f)
#define RHI (8.0f)

// ==== K_A: blocks 0..NAH-1: register-load + LDS hist + wave-scan + global-range
//           reservation (1 atomic per bucket) + direct bucket-major scatter to elist2.
//          blocks NAH..NAH+G_TAB-1: MLP table (K-split GEMV). ====
__global__ __launch_bounds__(1024)
void kA(const int4* __restrict__ src4, const int4* __restrict__ dst4,
        unsigned* __restrict__ elist2, unsigned* __restrict__ gcnt,
        const float* __restrict__ W0, const float* __restrict__ B0,
        const float* __restrict__ W1, const float* __restrict__ B1,
        const float* __restrict__ W2, const float* __restrict__ B2,
        const float* __restrict__ W3, const float* __restrict__ B3,
        const float* __restrict__ W4, const float* __restrict__ B4,
        const float* __restrict__ W5, const float* __restrict__ B5,
        const float* __restrict__ W6, const float* __restrict__ B6,
        const float* __restrict__ W7, const float* __restrict__ B7,
        float* __restrict__ T) {
    __shared__ unsigned smu[2048];      // sort: h/delta(512) | cur(512); table: 1540 floats
    const int tid = threadIdx.x;
    const int b = blockIdx.x;

    if (b < NAH) {
        unsigned* h = smu;              // counts, then reused as delta (global - local offset)
        unsigned* cur = smu + 512;      // local exclusive offsets -> atomic cursors
        if (tid < 512) h[tid] = 0u;
        __syncthreads();
        // load this block's 8192 edges into registers (one global read)
        int base0 = b * (EPB / 4);
        int4 dv[2], sv[2];
        #pragma unroll
        for (int i = 0; i < 2; i++) {
            dv[i] = dst4[base0 + i * 1024 + tid];
            sv[i] = src4[base0 + i * 1024 + tid];
        }
        #pragma unroll
        for (int i = 0; i < 2; i++) {
            atomicAdd(&h[dv[i].x >> 9], 1u);
            atomicAdd(&h[dv[i].y >> 9], 1u);
            atomicAdd(&h[dv[i].z >> 9], 1u);
            atomicAdd(&h[dv[i].w >> 9], 1u);
        }
        __syncthreads();
        // single-wave exclusive scan: lane owns 8 consecutive bins
        if (tid < 64) {
            unsigned v[8];
            unsigned run = 0;
            #pragma unroll
            for (int i = 0; i < 8; i++) {
                unsigned c = h[tid * 8 + i];
                v[i] = run;
                run += c;
            }
            unsigned inc = run;
            #pragma unroll
            for (int o = 1; o < 64; o <<= 1) {
                unsigned u = __shfl_up(inc, o);
                if (tid >= o) inc += u;
            }
            unsigned cbase = inc - run;
            #pragma unroll
            for (int i = 0; i < 8; i++)
                cur[tid * 8 + i] = cbase + v[i];
        }
        __syncthreads();
        // reserve a disjoint range in bucket tid's global region; delta maps local->global
        if (tid < 512) {
            unsigned c = h[tid];
            unsigned gb = atomicAdd(&gcnt[tid], c);
            h[tid] = (unsigned)(tid * CAP) + gb - cur[tid];   // delta
        }
        __syncthreads();
        // direct bucket-major scatter: elist2[delta[bk] + local_pos] = (src<<9)|dst_lo
        #pragma unroll
        for (int i = 0; i < 2; i++) {
            unsigned bk, p;
            bk = (unsigned)dv[i].x >> 9; p = atomicAdd(&cur[bk], 1u);
            elist2[h[bk] + p] = ((unsigned)sv[i].x << 9) | ((unsigned)dv[i].x & 511u);
            bk = (unsigned)dv[i].y >> 9; p = atomicAdd(&cur[bk], 1u);
            elist2[h[bk] + p] = ((unsigned)sv[i].y << 9) | ((unsigned)dv[i].y & 511u);
            bk = (unsigned)dv[i].z >> 9; p = atomicAdd(&cur[bk], 1u);
            elist2[h[bk] + p] = ((unsigned)sv[i].z << 9) | ((unsigned)dv[i].z & 511u);
            bk = (unsigned)dv[i].w >> 9; p = atomicAdd(&cur[bk], 1u);
            elist2[h[bk] + p] = ((unsigned)sv[i].w << 9) | ((unsigned)dv[i].w & 511u);
        }
    } else {
        // ---- table point p: 4-way K-split GEMV per layer ----
        float* smf = (float*)smu;        // hs[2][256] | ps[4][256] | scr[4]
        const int p = b - NAH;
        const int g = tid >> 8;          // K-group 0..3
        const int n = tid & 255;         // output neuron (active n<200)
        float* hs = smf;
        float* ps = smf + 512;
        float step = (RHI - RLO) / (float)(G_TAB - 1);
        float gp = RLO + (float)p * step;

        if (g == 0 && n < HID) hs[n] = fmaxf(fmaf(gp, W0[n], B0[n]), 0.f);
        __syncthreads();

        const float* Ws[6] = {W1, W2, W3, W4, W5, W6};
        const float* Bs[6] = {B1, B2, B3, B4, B5, B6};
        int cur = 0;
        for (int l = 0; l < 6; l++) {
            float part = 0.f;
            if (n < HID) {
                const float* Wp = Ws[l] + (g * 50) * HID + n;
                const float* hp = hs + cur * 256 + g * 50;
                #pragma unroll
                for (int k = 0; k < 50; k++)
                    part = fmaf(hp[k], Wp[k * HID], part);
            }
            ps[g * 256 + n] = part;
            __syncthreads();
            if (g == 0 && n < HID) {
                float acc = ps[n] + ps[256 + n] + ps[512 + n] + ps[768 + n] + Bs[l][n];
                hs[(1 - cur) * 256 + n] = fmaxf(acc, 0.f);
            }
            __syncthreads();
            cur = 1 - cur;
        }
        if (g == 0) {
            float part = (n < HID) ? hs[cur * 256 + n] * W7[n] : 0.f;
            #pragma unroll
            for (int o = 32; o > 0; o >>= 1) part += __shfl_down(part, o);
            float* w4 = smf + 1536;
            if ((n & 63) == 0) w4[n >> 6] = part;
        }
        __syncthreads();
        if (tid == 0) T[p] = smf[1536] + smf[1537] + smf[1538] + smf[1539] + B7[0];
    }
}

// ==== K_BC (cooperative): block k = bucket k. One contiguous coalesced read of the
//      bucket's edges into registers; count degree once; y = x*rsqrt(deg+1);
//      grid.sync(); accumulate y[src] from registers; interp/sigmoid. ====
__global__ __launch_bounds__(512, 4)
void kBC(const unsigned* __restrict__ gcnt, const unsigned* __restrict__ elist2,
         const float* __restrict__ x, const float* __restrict__ T,
         float* __restrict__ y, float* __restrict__ out) {
    __shared__ unsigned cnt[512];
    __shared__ float accf[512];
    const int t = threadIdx.x;
    const int k = blockIdx.x;
    cnt[t] = 0u;
    accf[t] = 0.f;
    const unsigned m = gcnt[k];                       // edges in this bucket (~4096)
    const unsigned* ep = elist2 + (unsigned)k * CAP;
    unsigned ed[16];                                  // static-indexed, stays in VGPRs
    #pragma unroll
    for (int r = 0; r < 16; r++) {
        unsigned j = (unsigned)t + ((unsigned)r << 9);
        ed[r] = (j < m) ? ep[j] : 0xFFFFFFFFu;        // coalesced
    }
    __syncthreads();
    #pragma unroll
    for (int r = 0; r < 16; r++)
        if (ed[r] != 0xFFFFFFFFu) atomicAdd(&cnt[ed[r] & 511u], 1u);
    __syncthreads();
    const int i = (k << 9) + t;
    const float iv = rsqrtf((float)(cnt[t] + 1u));    // +1 self-loop
    const float ys = x[i] * iv;
    y[i] = ys;
    cg::this_grid().sync();                           // all y visible device-wide
    #pragma unroll
    for (int r = 0; r < 16; r++)
        if (ed[r] != 0xFFFFFFFFu) atomicAdd(&accf[ed[r] & 511u], y[ed[r] >> 9]);
    __syncthreads();
    const float inv_step = (float)(G_TAB - 1) / (RHI - RLO);
    float g = iv * (accf[t] + ys);                    // y_self = x*iv
    float u = (g - RLO) * inv_step;
    int j = min(max((int)u, 0), G_TAB - 2);
    float fr = u - (float)j;
    float logit = fmaf(fr, T[j + 1] - T[j], T[j]);
    out[i] = 1.f / (1.f + expf(-logit));
}

extern "C" void kernel_launch(void* const* d_in, const int* in_sizes, int n_in,
                              void* d_out, int out_size, void* d_ws, size_t ws_size,
                              hipStream_t stream) {
    const float* x = (const float*)d_in[0];
    const int* e = (const int*)d_in[1];          // int32 edge_index [2][E]
    const int* src = e;
    const int* dst = e + N_EDGES;
    const float* W0 = (const float*)d_in[2];  const float* B0 = (const float*)d_in[3];
    const float* W1 = (const float*)d_in[4];  const float* B1 = (const float*)d_in[5];
    const float* W2 = (const float*)d_in[6];  const float* B2 = (const float*)d_in[7];
    const float* W3 = (const float*)d_in[8];  const float* B3 = (const float*)d_in[9];
    const float* W4 = (const float*)d_in[10]; const float* B4 = (const float*)d_in[11];
    const float* W5 = (const float*)d_in[12]; const float* B5 = (const float*)d_in[13];
    const float* W6 = (const float*)d_in[14]; const float* B6 = (const float*)d_in[15];
    const float* W7 = (const float*)d_in[16]; const float* B7 = (const float*)d_in[17];
    float* out = (float*)d_out;

    // ws layout (4B words): elist2(NB*CAP) | gcnt(NB) | y(N) | T(G_TAB)
    unsigned* wsu = (unsigned*)d_ws;
    unsigned* elist2 = wsu;
    unsigned* gcnt = elist2 + (size_t)NB * CAP;
    float* y = (float*)(gcnt + NB);
    float* T = y + N_NODES;

    hipMemsetAsync(gcnt, 0, NB * sizeof(unsigned), stream);
    kA<<<NAH + G_TAB, 1024, 0, stream>>>(
        (const int4*)src, (const int4*)dst, elist2, gcnt,
        W0, B0, W1, B1, W2, B2, W3, B3, W4, B4, W5, B5, W6, B6, W7, B7, T);

    const unsigned* a0 = gcnt;
    const unsigned* a1 = elist2;
    const float* a2 = x;
    const float* a3 = T;
    float* a4 = y;
    float* a5 = out;
    void* args[6] = {(void*)&a0, (void*)&a1, (void*)&a2, (void*)&a3, (void*)&a4, (void*)&a5};
    hipLaunchCooperativeKernel((const void*)kBC, dim3(NB), dim3(512), args, 0, stream);
}

// Round 2
// 214.256 us; speedup vs baseline: 1.0176x; 1.0176x over previous
//
#include <hip/hip_runtime.h>
#include <hip/hip_cooperative_groups.h>
#include <math.h>

namespace cg = cooperative_groups;

#define N_NODES 262144
#define N_EDGES 2097152
#define NB 512                  // dst buckets (dst >> 9), 512 nodes each
#define NAH 256                 // sort slice blocks
#define EPB (N_EDGES / NAH)     // 8192 edges per slice
#define CAP 8192                // per-bucket region capacity in elist2 (avg 4096)
#define HID 200
#define G_TAB 128
#define RLO (-8.0f)
#define RHI (8.0f)

// ==== K_A: blocks 0..NAH-1: register-load + LDS hist + wave-scan + LDS sort +
//           global range reservation (1 atomic per bucket) + coalesced segment
//           copy-out into globally bucket-major elist2.
//          blocks NAH..NAH+G_TAB-1: MLP table (K-split GEMV). ====
__global__ __launch_bounds__(1024)
void kA(const int4* __restrict__ src4, const int4* __restrict__ dst4,
        unsigned* __restrict__ elist2, unsigned* __restrict__ gcnt,
        const float* __restrict__ W0, const float* __restrict__ B0,
        const float* __restrict__ W1, const float* __restrict__ B1,
        const float* __restrict__ W2, const float* __restrict__ B2,
        const float* __restrict__ W3, const float* __restrict__ B3,
        const float* __restrict__ W4, const float* __restrict__ B4,
        const float* __restrict__ W5, const float* __restrict__ B5,
        const float* __restrict__ W6, const float* __restrict__ B6,
        const float* __restrict__ W7, const float* __restrict__ B7,
        float* __restrict__ T) {
    __shared__ unsigned smu[512 + 512 + EPB];   // delta | cur | sorted = 36 KB
    const int tid = threadIdx.x;
    const int b = blockIdx.x;

    if (b < NAH) {
        unsigned* dl = smu;             // counts -> delta (global - local start)
        unsigned* cur = smu + 512;      // exclusive offsets -> atomic cursors -> ends
        unsigned* sorted = smu + 1024;
        if (tid < 512) dl[tid] = 0u;
        __syncthreads();
        // load this block's 8192 edges into registers (one global read)
        int base0 = b * (EPB / 4);
        int4 dv[2], sv[2];
        #pragma unroll
        for (int i = 0; i < 2; i++) {
            dv[i] = dst4[base0 + i * 1024 + tid];
            sv[i] = src4[base0 + i * 1024 + tid];
        }
        #pragma unroll
        for (int i = 0; i < 2; i++) {
            atomicAdd(&dl[dv[i].x >> 9], 1u);
            atomicAdd(&dl[dv[i].y >> 9], 1u);
            atomicAdd(&dl[dv[i].z >> 9], 1u);
            atomicAdd(&dl[dv[i].w >> 9], 1u);
        }
        __syncthreads();
        // single-wave exclusive scan: lane owns 8 consecutive bins
        if (tid < 64) {
            unsigned v[8];
            unsigned run = 0;
            #pragma unroll
            for (int i = 0; i < 8; i++) {
                unsigned c = dl[tid * 8 + i];
                v[i] = run;
                run += c;
            }
            unsigned inc = run;
            #pragma unroll
            for (int o = 1; o < 64; o <<= 1) {
                unsigned u = __shfl_up(inc, o);
                if (tid >= o) inc += u;
            }
            unsigned cbase = inc - run;
            #pragma unroll
            for (int i = 0; i < 8; i++)
                cur[tid * 8 + i] = cbase + v[i];
        }
        __syncthreads();
        // reserve disjoint range in bucket tid's global region; delta: local->global
        if (tid < 512) {
            unsigned c = dl[tid];
            unsigned gb = atomicAdd(&gcnt[tid], c);
            dl[tid] = (unsigned)(tid * CAP) + gb - cur[tid];
        }
        __syncthreads();
        // place into LDS staging, sorted by bucket (cur advances to segment ends)
        #pragma unroll
        for (int i = 0; i < 2; i++) {
            unsigned p;
            p = atomicAdd(&cur[dv[i].x >> 9], 1u);
            sorted[p] = ((unsigned)sv[i].x << 9) | ((unsigned)dv[i].x & 511u);
            p = atomicAdd(&cur[dv[i].y >> 9], 1u);
            sorted[p] = ((unsigned)sv[i].y << 9) | ((unsigned)dv[i].y & 511u);
            p = atomicAdd(&cur[dv[i].z >> 9], 1u);
            sorted[p] = ((unsigned)sv[i].z << 9) | ((unsigned)dv[i].z & 511u);
            p = atomicAdd(&cur[dv[i].w >> 9], 1u);
            sorted[p] = ((unsigned)sv[i].w << 9) | ((unsigned)dv[i].w & 511u);
        }
        __syncthreads();
        // copy-out: thread owns 8 consecutive sorted positions; cur[] now holds
        // segment ENDS. Binary search once, then linear advance across boundaries.
        // Global addr = delta[bk] + q -> contiguous runs, coalesced.
        {
            unsigned q0 = (unsigned)tid * 8u;
            int lo = 0, hi = 511;
            #pragma unroll
            for (int s = 0; s < 9; s++) {
                int mid = (lo + hi) >> 1;
                if (cur[mid] <= q0) lo = mid + 1; else hi = mid;
            }
            unsigned bk = (unsigned)lo;
            #pragma unroll
            for (int i = 0; i < 8; i++) {
                unsigned q = q0 + (unsigned)i;
                while (q >= cur[bk]) bk++;
                elist2[dl[bk] + q] = sorted[q];
            }
        }
    } else {
        // ---- table point p: 4-way K-split GEMV per layer ----
        float* smf = (float*)smu;        // hs[2][256] | ps[4][256] | scr[4]
        const int p = b - NAH;
        const int g = tid >> 8;          // K-group 0..3
        const int n = tid & 255;         // output neuron (active n<200)
        float* hs = smf;
        float* ps = smf + 512;
        float step = (RHI - RLO) / (float)(G_TAB - 1);
        float gp = RLO + (float)p * step;

        if (g == 0 && n < HID) hs[n] = fmaxf(fmaf(gp, W0[n], B0[n]), 0.f);
        __syncthreads();

        const float* Ws[6] = {W1, W2, W3, W4, W5, W6};
        const float* Bs[6] = {B1, B2, B3, B4, B5, B6};
        int cur = 0;
        for (int l = 0; l < 6; l++) {
            float part = 0.f;
            if (n < HID) {
                const float* Wp = Ws[l] + (g * 50) * HID + n;
                const float* hp = hs + cur * 256 + g * 50;
                #pragma unroll
                for (int k = 0; k < 50; k++)
                    part = fmaf(hp[k], Wp[k * HID], part);
            }
            ps[g * 256 + n] = part;
            __syncthreads();
            if (g == 0 && n < HID) {
                float acc = ps[n] + ps[256 + n] + ps[512 + n] + ps[768 + n] + Bs[l][n];
                hs[(1 - cur) * 256 + n] = fmaxf(acc, 0.f);
            }
            __syncthreads();
            cur = 1 - cur;
        }
        if (g == 0) {
            float part = (n < HID) ? hs[cur * 256 + n] * W7[n] : 0.f;
            #pragma unroll
            for (int o = 32; o > 0; o >>= 1) part += __shfl_down(part, o);
            float* w4 = smf + 1536;
            if ((n & 63) == 0) w4[n >> 6] = part;
        }
        __syncthreads();
        if (tid == 0) T[p] = smf[1536] + smf[1537] + smf[1538] + smf[1539] + B7[0];
    }
}

// ==== K_BC (cooperative): block k = bucket k. One contiguous coalesced read of the
//      bucket's edges into registers; count degree once; y = x*rsqrt(deg+1);
//      grid.sync(); accumulate y[src] from registers; interp/sigmoid. ====
__global__ __launch_bounds__(512, 4)
void kBC(const unsigned* __restrict__ gcnt, const unsigned* __restrict__ elist2,
         const float* __restrict__ x, const float* __restrict__ T,
         float* __restrict__ y, float* __restrict__ out) {
    __shared__ unsigned cnt[512];
    __shared__ float accf[512];
    const int t = threadIdx.x;
    const int k = blockIdx.x;
    cnt[t] = 0u;
    accf[t] = 0.f;
    const unsigned m = gcnt[k];                       // edges in this bucket (~4096)
    const unsigned* ep = elist2 + (unsigned)k * CAP;
    unsigned ed[16];                                  // static-indexed, stays in VGPRs
    #pragma unroll
    for (int r = 0; r < 16; r++) {
        unsigned j = (unsigned)t + ((unsigned)r << 9);
        ed[r] = (j < m) ? ep[j] : 0xFFFFFFFFu;        // coalesced
    }
    __syncthreads();
    #pragma unroll
    for (int r = 0; r < 16; r++)
        if (ed[r] != 0xFFFFFFFFu) atomicAdd(&cnt[ed[r] & 511u], 1u);
    __syncthreads();
    const int i = (k << 9) + t;
    const float iv = rsqrtf((float)(cnt[t] + 1u));    // +1 self-loop
    const float ys = x[i] * iv;
    y[i] = ys;
    cg::this_grid().sync();                           // all y visible device-wide
    #pragma unroll
    for (int r = 0; r < 16; r++)
        if (ed[r] != 0xFFFFFFFFu) atomicAdd(&accf[ed[r] & 511u], y[ed[r] >> 9]);
    __syncthreads();
    const float inv_step = (float)(G_TAB - 1) / (RHI - RLO);
    float g = iv * (accf[t] + ys);                    // y_self = x*iv
    float u = (g - RLO) * inv_step;
    int j = min(max((int)u, 0), G_TAB - 2);
    float fr = u - (float)j;
    float logit = fmaf(fr, T[j + 1] - T[j], T[j]);
    out[i] = 1.f / (1.f + expf(-logit));
}

extern "C" void kernel_launch(void* const* d_in, const int* in_sizes, int n_in,
                              void* d_out, int out_size, void* d_ws, size_t ws_size,
                              hipStream_t stream) {
    const float* x = (const float*)d_in[0];
    const int* e = (const int*)d_in[1];          // int32 edge_index [2][E]
    const int* src = e;
    const int* dst = e + N_EDGES;
    const float* W0 = (const float*)d_in[2];  const float* B0 = (const float*)d_in[3];
    const float* W1 = (const float*)d_in[4];  const float* B1 = (const float*)d_in[5];
    const float* W2 = (const float*)d_in[6];  const float* B2 = (const float*)d_in[7];
    const float* W3 = (const float*)d_in[8];  const float* B3 = (const float*)d_in[9];
    const float* W4 = (const float*)d_in[10]; const float* B4 = (const float*)d_in[11];
    const float* W5 = (const float*)d_in[12]; const float* B5 = (const float*)d_in[13];
    const float* W6 = (const float*)d_in[14]; const float* B6 = (const float*)d_in[15];
    const float* W7 = (const float*)d_in[16]; const float* B7 = (const float*)d_in[17];
    float* out = (float*)d_out;

    // ws layout (4B words): elist2(NB*CAP) | gcnt(NB) | y(N) | T(G_TAB)
    unsigned* wsu = (unsigned*)d_ws;
    unsigned* elist2 = wsu;
    unsigned* gcnt = elist2 + (size_t)NB * CAP;
    float* y = (float*)(gcnt + NB);
    float* T = y + N_NODES;

    hipMemsetAsync(gcnt, 0, NB * sizeof(unsigned), stream);
    kA<<<NAH + G_TAB, 1024, 0, stream>>>(
        (const int4*)src, (const int4*)dst, elist2, gcnt,
        W0, B0, W1, B1, W2, B2, W3, B3, W4, B4, W5, B5, W6, B6, W7, B7, T);

    const unsigned* a0 = gcnt;
    const unsigned* a1 = elist2;
    const float* a2 = x;
    const float* a3 = T;
    float* a4 = y;
    float* a5 = out;
    void* args[6] = {(void*)&a0, (void*)&a1, (void*)&a2, (void*)&a3, (void*)&a4, (void*)&a5};
    hipLaunchCooperativeKernel((const void*)kBC, dim3(NB), dim3(512), args, 0, stream);
}

// Round 3
// 144.802 us; speedup vs baseline: 1.5057x; 1.4797x over previous
//
#include <hip/hip_runtime.h>
#include <math.h>

#define N_NODES 262144
#define N_EDGES 2097152
#define NB 512                  // dst buckets (dst >> 9), 512 nodes each
#define NAH 256                 // sort slice blocks
#define EPB (N_EDGES / NAH)     // 8192 edges per slice
#define CAP 8192                // per-bucket region capacity in elist2 (avg 4096)
#define HID 200
#define G_TAB 128
#define RLO (-8.0f)
#define RHI (8.0f)

// ==== K_A: blocks 0..NAH-1: register-load + LDS hist + wave-scan + LDS sort +
//           global range reservation (1 atomic per bucket) + coalesced segment
//           copy-out into globally bucket-major elist2.
//          blocks NAH..NAH+G_TAB-1: MLP table (K-split GEMV). ====
__global__ __launch_bounds__(1024)
void kA(const int4* __restrict__ src4, const int4* __restrict__ dst4,
        unsigned* __restrict__ elist2, unsigned* __restrict__ gcnt,
        const float* __restrict__ W0, const float* __restrict__ B0,
        const float* __restrict__ W1, const float* __restrict__ B1,
        const float* __restrict__ W2, const float* __restrict__ B2,
        const float* __restrict__ W3, const float* __restrict__ B3,
        const float* __restrict__ W4, const float* __restrict__ B4,
        const float* __restrict__ W5, const float* __restrict__ B5,
        const float* __restrict__ W6, const float* __restrict__ B6,
        const float* __restrict__ W7, const float* __restrict__ B7,
        float* __restrict__ T) {
    __shared__ unsigned smu[512 + 512 + EPB];   // delta | cur | sorted = 36 KB
    const int tid = threadIdx.x;
    const int b = blockIdx.x;

    if (b < NAH) {
        unsigned* dl = smu;             // counts -> delta (global - local start)
        unsigned* cur = smu + 512;      // exclusive offsets -> atomic cursors -> ends
        unsigned* sorted = smu + 1024;
        if (tid < 512) dl[tid] = 0u;
        __syncthreads();
        // load this block's 8192 edges into registers (one global read)
        int base0 = b * (EPB / 4);
        int4 dv[2], sv[2];
        #pragma unroll
        for (int i = 0; i < 2; i++) {
            dv[i] = dst4[base0 + i * 1024 + tid];
            sv[i] = src4[base0 + i * 1024 + tid];
        }
        #pragma unroll
        for (int i = 0; i < 2; i++) {
            atomicAdd(&dl[dv[i].x >> 9], 1u);
            atomicAdd(&dl[dv[i].y >> 9], 1u);
            atomicAdd(&dl[dv[i].z >> 9], 1u);
            atomicAdd(&dl[dv[i].w >> 9], 1u);
        }
        __syncthreads();
        // single-wave exclusive scan: lane owns 8 consecutive bins
        if (tid < 64) {
            unsigned v[8];
            unsigned run = 0;
            #pragma unroll
            for (int i = 0; i < 8; i++) {
                unsigned c = dl[tid * 8 + i];
                v[i] = run;
                run += c;
            }
            unsigned inc = run;
            #pragma unroll
            for (int o = 1; o < 64; o <<= 1) {
                unsigned u = __shfl_up(inc, o);
                if (tid >= o) inc += u;
            }
            unsigned cbase = inc - run;
            #pragma unroll
            for (int i = 0; i < 8; i++)
                cur[tid * 8 + i] = cbase + v[i];
        }
        __syncthreads();
        // reserve disjoint range in bucket tid's global region; delta: local->global
        if (tid < 512) {
            unsigned c = dl[tid];
            unsigned gb = atomicAdd(&gcnt[tid], c);
            dl[tid] = (unsigned)(tid * CAP) + gb - cur[tid];
        }
        __syncthreads();
        // place into LDS staging, sorted by bucket (cur advances to segment ends)
        #pragma unroll
        for (int i = 0; i < 2; i++) {
            unsigned p;
            p = atomicAdd(&cur[dv[i].x >> 9], 1u);
            sorted[p] = ((unsigned)sv[i].x << 9) | ((unsigned)dv[i].x & 511u);
            p = atomicAdd(&cur[dv[i].y >> 9], 1u);
            sorted[p] = ((unsigned)sv[i].y << 9) | ((unsigned)dv[i].y & 511u);
            p = atomicAdd(&cur[dv[i].z >> 9], 1u);
            sorted[p] = ((unsigned)sv[i].z << 9) | ((unsigned)dv[i].z & 511u);
            p = atomicAdd(&cur[dv[i].w >> 9], 1u);
            sorted[p] = ((unsigned)sv[i].w << 9) | ((unsigned)dv[i].w & 511u);
        }
        __syncthreads();
        // copy-out: thread owns 8 consecutive sorted positions; cur[] now holds
        // segment ENDS. Binary search once, then linear advance across boundaries.
        // Global addr = delta[bk] + q -> contiguous runs, coalesced.
        {
            unsigned q0 = (unsigned)tid * 8u;
            int lo = 0, hi = 511;
            #pragma unroll
            for (int s = 0; s < 9; s++) {
                int mid = (lo + hi) >> 1;
                if (cur[mid] <= q0) lo = mid + 1; else hi = mid;
            }
            unsigned bk = (unsigned)lo;
            #pragma unroll
            for (int i = 0; i < 8; i++) {
                unsigned q = q0 + (unsigned)i;
                while (q >= cur[bk]) bk++;
                elist2[dl[bk] + q] = sorted[q];
            }
        }
    } else {
        // ---- table point p: 4-way K-split GEMV per layer ----
        float* smf = (float*)smu;        // hs[2][256] | ps[4][256] | scr[4]
        const int p = b - NAH;
        const int g = tid >> 8;          // K-group 0..3
        const int n = tid & 255;         // output neuron (active n<200)
        float* hs = smf;
        float* ps = smf + 512;
        float step = (RHI - RLO) / (float)(G_TAB - 1);
        float gp = RLO + (float)p * step;

        if (g == 0 && n < HID) hs[n] = fmaxf(fmaf(gp, W0[n], B0[n]), 0.f);
        __syncthreads();

        const float* Ws[6] = {W1, W2, W3, W4, W5, W6};
        const float* Bs[6] = {B1, B2, B3, B4, B5, B6};
        int cur = 0;
        for (int l = 0; l < 6; l++) {
            float part = 0.f;
            if (n < HID) {
                const float* Wp = Ws[l] + (g * 50) * HID + n;
                const float* hp = hs + cur * 256 + g * 50;
                #pragma unroll
                for (int k = 0; k < 50; k++)
                    part = fmaf(hp[k], Wp[k * HID], part);
            }
            ps[g * 256 + n] = part;
            __syncthreads();
            if (g == 0 && n < HID) {
                float acc = ps[n] + ps[256 + n] + ps[512 + n] + ps[768 + n] + Bs[l][n];
                hs[(1 - cur) * 256 + n] = fmaxf(acc, 0.f);
            }
            __syncthreads();
            cur = 1 - cur;
        }
        if (g == 0) {
            float part = (n < HID) ? hs[cur * 256 + n] * W7[n] : 0.f;
            #pragma unroll
            for (int o = 32; o > 0; o >>= 1) part += __shfl_down(part, o);
            float* w4 = smf + 1536;
            if ((n & 63) == 0) w4[n >> 6] = part;
        }
        __syncthreads();
        if (tid == 0) T[p] = smf[1536] + smf[1537] + smf[1538] + smf[1539] + B7[0];
    }
}

// ==== K_B2: block k = bucket k. Coalesced read of bucket edges; count degree
//            once in LDS; write y = x*rsqrt(deg+1) and iv = rsqrt(deg+1). ====
__global__ __launch_bounds__(512)
void kB2(const unsigned* __restrict__ gcnt, const unsigned* __restrict__ elist2,
         const float* __restrict__ x, float* __restrict__ y, float* __restrict__ ivv) {
    __shared__ unsigned cnt[512];
    const int t = threadIdx.x;
    const int k = blockIdx.x;
    cnt[t] = 0u;
    __syncthreads();
    const unsigned m = gcnt[k];
    const unsigned* ep = elist2 + (size_t)k * CAP;
    for (unsigned j = (unsigned)t; j < m; j += 512u)
        atomicAdd(&cnt[ep[j] & 511u], 1u);
    __syncthreads();
    const int i = (k << 9) + t;
    const float iv = rsqrtf((float)(cnt[t] + 1u));    // +1 self-loop
    ivv[i] = iv;
    y[i] = x[i] * iv;
}

// ==== K_C2: block k = bucket k. Coalesced re-read; accumulate y[src] in LDS;
//            g = iv*(acc + y_self); table interp; sigmoid. No re-count. ====
__global__ __launch_bounds__(512)
void kC2(const unsigned* __restrict__ gcnt, const unsigned* __restrict__ elist2,
         const float* __restrict__ y, const float* __restrict__ ivv,
         const float* __restrict__ T, float* __restrict__ out) {
    __shared__ float accf[512];
    const int t = threadIdx.x;
    const int k = blockIdx.x;
    accf[t] = 0.f;
    __syncthreads();
    const unsigned m = gcnt[k];
    const unsigned* ep = elist2 + (size_t)k * CAP;
    for (unsigned j = (unsigned)t; j < m; j += 512u) {
        unsigned p = ep[j];
        atomicAdd(&accf[p & 511u], y[p >> 9]);
    }
    __syncthreads();
    const float inv_step = (float)(G_TAB - 1) / (RHI - RLO);
    const int i = (k << 9) + t;
    float g = ivv[i] * (accf[t] + y[i]);              // y_self = x*iv
    float u = (g - RLO) * inv_step;
    int j = min(max((int)u, 0), G_TAB - 2);
    float fr = u - (float)j;
    float logit = fmaf(fr, T[j + 1] - T[j], T[j]);
    out[i] = 1.f / (1.f + expf(-logit));
}

extern "C" void kernel_launch(void* const* d_in, const int* in_sizes, int n_in,
                              void* d_out, int out_size, void* d_ws, size_t ws_size,
                              hipStream_t stream) {
    const float* x = (const float*)d_in[0];
    const int* e = (const int*)d_in[1];          // int32 edge_index [2][E]
    const int* src = e;
    const int* dst = e + N_EDGES;
    const float* W0 = (const float*)d_in[2];  const float* B0 = (const float*)d_in[3];
    const float* W1 = (const float*)d_in[4];  const float* B1 = (const float*)d_in[5];
    const float* W2 = (const float*)d_in[6];  const float* B2 = (const float*)d_in[7];
    const float* W3 = (const float*)d_in[8];  const float* B3 = (const float*)d_in[9];
    const float* W4 = (const float*)d_in[10]; const float* B4 = (const float*)d_in[11];
    const float* W5 = (const float*)d_in[12]; const float* B5 = (const float*)d_in[13];
    const float* W6 = (const float*)d_in[14]; const float* B6 = (const float*)d_in[15];
    const float* W7 = (const float*)d_in[16]; const float* B7 = (const float*)d_in[17];
    float* out = (float*)d_out;

    // ws layout (4B words): elist2(NB*CAP) | gcnt(NB) | y(N) | iv(N) | T(G_TAB)
    unsigned* wsu = (unsigned*)d_ws;
    unsigned* elist2 = wsu;
    unsigned* gcnt = elist2 + (size_t)NB * CAP;
    float* y = (float*)(gcnt + NB);
    float* ivv = y + N_NODES;
    float* T = ivv + N_NODES;

    hipMemsetAsync(gcnt, 0, NB * sizeof(unsigned), stream);
    kA<<<NAH + G_TAB, 1024, 0, stream>>>(
        (const int4*)src, (const int4*)dst, elist2, gcnt,
        W0, B0, W1, B1, W2, B2, W3, B3, W4, B4, W5, B5, W6, B6, W7, B7, T);
    kB2<<<NB, 512, 0, stream>>>(gcnt, elist2, x, y, ivv);
    kC2<<<NB, 512, 0, stream>>>(gcnt, elist2, y, ivv, T, out);
}